// Round 9
// baseline (497.748 us; speedup 1.0000x reference)
//
#include <hip/hip_runtime.h>

#define Hdim 1024
#define BB 64
#define SS 256
#define RR 196
#define MD (BB * SS)   // 16384
#define MI (BB * RR)   // 12544

typedef __attribute__((ext_vector_type(8))) short short8;
typedef __attribute__((ext_vector_type(4))) float floatx4;
typedef unsigned short us;

__device__ __forceinline__ unsigned short f2bf(float f) {
  unsigned int u = __float_as_uint(f);
  unsigned int r = 0x7FFFu + ((u >> 16) & 1u);
  return (unsigned short)((u + r) >> 16);
}

__device__ __forceinline__ float fast_tanh(float x) {
  x = fminf(15.f, fmaxf(-15.f, x));
  float e = __expf(2.f * x);
  return (e - 1.f) / (e + 1.f);
}

#define GLOAD16(g, l) __builtin_amdgcn_global_load_lds( \
    (const __attribute__((address_space(1))) unsigned int*)(g), \
    (__attribute__((address_space(3))) unsigned int*)(l), 16, 0, 0)

#define MEMFENCE asm volatile("" ::: "memory")

// ---------------- prep: all fp32->bf16 converts + zero scores, one kernel ---
__global__ __launch_bounds__(256) void prep_kernel(
    const float4* __restrict__ dns, const float4* __restrict__ img,
    const float4* __restrict__ Wd1, const float4* __restrict__ Wi2,
    uint4* __restrict__ dns_bf, uint4* __restrict__ img_bf,
    uint4* __restrict__ wd1_bf, uint4* __restrict__ wi2_bf,
    float4* __restrict__ scz)
{
  constexpr int N0 = (MD * Hdim) / 8;              // dns units (8 floats each)
  constexpr int N1 = N0 + (MI * Hdim) / 8;
  constexpr int N2 = N1 + (Hdim * Hdim) / 8;
  constexpr int N3 = N2 + (Hdim * Hdim) / 8;
  constexpr int N4 = N3 + (MD + MI) / 8;           // zero units
  const int stride = gridDim.x * 256;
  for (int i = blockIdx.x * 256 + threadIdx.x; i < N4; i += stride) {
    if (i < N3) {
      const float4* src; uint4* dst; int li;
      if (i < N0)      { src = dns; dst = dns_bf; li = i; }
      else if (i < N1) { src = img; dst = img_bf; li = i - N0; }
      else if (i < N2) { src = Wd1; dst = wd1_bf; li = i - N1; }
      else             { src = Wi2; dst = wi2_bf; li = i - N2; }
      const float4 a = src[2 * li];
      const float4 b = src[2 * li + 1];
      uint4 o;
      o.x = (unsigned)f2bf(a.x) | ((unsigned)f2bf(a.y) << 16);
      o.y = (unsigned)f2bf(a.z) | ((unsigned)f2bf(a.w) << 16);
      o.z = (unsigned)f2bf(b.x) | ((unsigned)f2bf(b.y) << 16);
      o.w = (unsigned)f2bf(b.z) | ((unsigned)f2bf(b.w) << 16);
      dst[li] = o;
    } else {
      const int li = i - N3;
      const float4 z4 = {0.f, 0.f, 0.f, 0.f};
      scz[2 * li]     = z4;
      scz[2 * li + 1] = z4;
    }
  }
}

// ---------------- 256x256 bf16 GEMM, BK=32, 2 blocks/CU -----------------
// BM=BN=256, BK=32, 512 threads (8 waves, 2Mx4N, wave tile 128x64).
// LDS 64KB: A [2 dbuf][256][32], B same at +16384 elems -> 2 blocks/CU
// (the round-7 128KB variant allowed only 1 block/CU; all stalls were
// uncovered). 2 phases per K-tile, 16-MFMA clusters between raw barriers;
// stages for T+1 (both A and B) issue in P1 targeting dbuf d^1 (freed at
// T-1 boundary); per-thread vmcnt(0) at P2 end (~1.5 phases slack);
// inter-block overlap covers the rest.
#define NB1 ((MD / 256) * 4)   // 256
#define NB2 ((MI / 256) * 4)   // 196

__global__ __launch_bounds__(512, 4) void gemm_score_8p(
    const us* __restrict__ X1, const us* __restrict__ W1,
    const float* __restrict__ bias1, const float* __restrict__ v1, float* sc1,
    const us* __restrict__ X2, const us* __restrict__ W2,
    const float* __restrict__ bias2, const float* __restrict__ v2, float* sc2)
{
  __shared__ us LDS[32768];   // 64 KB

  // bijective XCD-chunked swizzle (m204): nwg=452, q=56, r=4
  const int nwg = gridDim.x;
  const int q = nwg >> 3, rr = nwg & 7;
  const int xcd = blockIdx.x & 7, idx = blockIdx.x >> 3;
  const int wg = (xcd < rr ? xcd * (q + 1) : rr * (q + 1) + (xcd - rr) * q) + idx;

  const us* Xb; const us* Wb; const float* bias; const float* vatt; float* scores;
  int mt, nt;
  if (wg < NB1) {
    Xb = X1; Wb = W1; bias = bias1; vatt = v1; scores = sc1;
    mt = wg >> 2; nt = wg & 3;
  } else {
    const int w2 = wg - NB1;
    Xb = X2; Wb = W2; bias = bias2; vatt = v2; scores = sc2;
    mt = w2 >> 2; nt = w2 & 3;
  }
  const long m0 = (long)mt * 256;
  const long n0 = (long)nt * 256;

  const int tid  = threadIdx.x;
  const int lane = tid & 63;
  const int w    = tid >> 6;     // wave 0..7
  const int wm   = w >> 2;       // 0..1  (row half)
  const int wn   = w & 3;        // 0..3  (col quarter)

  // ---- staging geometry: rows of 32 elems = 4 slots of 8; XOR row&3 swizzle
  const int srow4 = (lane >> 2) & 3;                   // row&3 of this thread's row
  const int scol  = ((lane & 3) ^ srow4) * 8;          // pre-swizzled source slot
  const int tid8  = tid * 8;                           // linear LDS dest (elems)
  // c in {0,1}: rows c*128 + tid/4
  const us* gA0 = Xb + (m0 + 0   + (tid >> 2)) * Hdim + scol;
  const us* gA1 = Xb + (m0 + 128 + (tid >> 2)) * Hdim + scol;
  const us* gB0 = Wb + (n0 + 0   + (tid >> 2)) * Hdim + scol;
  const us* gB1 = Wb + (n0 + 128 + (tid >> 2)) * Hdim + scol;

#define STAGE_A(d, kk) do { \
    GLOAD16(gA0 + (kk), &LDS[(d) * 8192 + 0    + tid8]); \
    GLOAD16(gA1 + (kk), &LDS[(d) * 8192 + 4096 + tid8]); } while (0)
#define STAGE_B(d, kk) do { \
    GLOAD16(gB0 + (kk), &LDS[16384 + (d) * 8192 + 0    + tid8]); \
    GLOAD16(gB1 + (kk), &LDS[16384 + (d) * 8192 + 4096 + tid8]); } while (0)

  floatx4 acc[8][4];
  #pragma unroll
  for (int i = 0; i < 8; ++i)
    #pragma unroll
    for (int j = 0; j < 4; ++j)
      acc[i][j] = (floatx4){0.f, 0.f, 0.f, 0.f};

  const int frow = lane & 15;
  const int g    = lane >> 4;
  const int slotE = ((g ^ (frow & 3)) * 8);            // swizzled read slot (elems)
  const int aRow = (wm * 128 + frow) * 32 + slotE;     // + mf*16*32
  const int bRow = 16384 + (wn * 64 + frow) * 32 + slotE; // + nf*16*32

  // prologue: tile 0 -> dbuf 0
  STAGE_A(0, 0); STAGE_B(0, 0);
  asm volatile("s_waitcnt vmcnt(0)" ::: "memory");
  MEMFENCE; __builtin_amdgcn_s_barrier(); MEMFENCE;

  #pragma unroll 1
  for (int T = 0; T < 32; ++T) {
    const int d   = T & 1;
    const int kk1 = (T + 1) * 32;
    const int Ab  = d * 8192 + aRow;
    const int Bb  = d * 8192 + bRow;
    short8 a[4], b[4];

    // ---- P1: reads {A mf0-3, B nf0-3}; stage A+B(T+1); bar; 16 MFMA; bar
    #pragma unroll
    for (int mf = 0; mf < 4; ++mf) a[mf] = *(const short8*)&LDS[Ab + mf * 512];
    #pragma unroll
    for (int nf = 0; nf < 4; ++nf) b[nf] = *(const short8*)&LDS[Bb + nf * 512];
    if (T < 31) { STAGE_A(d ^ 1, kk1); STAGE_B(d ^ 1, kk1); }
    MEMFENCE; __builtin_amdgcn_s_barrier(); MEMFENCE;
    __builtin_amdgcn_s_setprio(1);
    #pragma unroll
    for (int mf = 0; mf < 4; ++mf)
      #pragma unroll
      for (int nf = 0; nf < 4; ++nf)
        acc[mf][nf] = __builtin_amdgcn_mfma_f32_16x16x32_bf16(a[mf], b[nf], acc[mf][nf], 0, 0, 0);
    __builtin_amdgcn_s_setprio(0);
    MEMFENCE; __builtin_amdgcn_s_barrier(); MEMFENCE;

    // ---- P2: reads {A mf4-7}; bar; 16 MFMA; vmcnt(0); boundary bar
    #pragma unroll
    for (int mf = 0; mf < 4; ++mf) a[mf] = *(const short8*)&LDS[Ab + (mf + 4) * 512];
    MEMFENCE; __builtin_amdgcn_s_barrier(); MEMFENCE;
    __builtin_amdgcn_s_setprio(1);
    #pragma unroll
    for (int mf = 0; mf < 4; ++mf)
      #pragma unroll
      for (int nf = 0; nf < 4; ++nf)
        acc[mf + 4][nf] = __builtin_amdgcn_mfma_f32_16x16x32_bf16(a[mf], b[nf], acc[mf + 4][nf], 0, 0, 0);
    __builtin_amdgcn_s_setprio(0);
    asm volatile("s_waitcnt vmcnt(0)" ::: "memory");   // own T+1 stages landed
    MEMFENCE; __builtin_amdgcn_s_barrier(); MEMFENCE;  // all waves' stages landed
  }

  // fused epilogue: tanh(C + bias) . vatt -> per-row partial, atomicAdd.
  // C/D layout: col = lane&15, row = (lane>>4)*4 + j
  const int rgrp = lane >> 4;
  #pragma unroll
  for (int mf = 0; mf < 8; ++mf) {
    float part[4] = {0.f, 0.f, 0.f, 0.f};
    #pragma unroll
    for (int nf = 0; nf < 4; ++nf) {
      const int n = (int)n0 + wn * 64 + nf * 16 + (lane & 15);
      const float bi = bias[n];
      const float vv = vatt[n];
      #pragma unroll
      for (int j = 0; j < 4; ++j)
        part[j] += fast_tanh(acc[mf][nf][j] + bi) * vv;
    }
    #pragma unroll
    for (int j = 0; j < 4; ++j) {
      float s = part[j];
      s += __shfl_xor(s, 1);
      s += __shfl_xor(s, 2);
      s += __shfl_xor(s, 4);
      s += __shfl_xor(s, 8);
      if ((lane & 15) == 0) {
        const int m = (int)m0 + wm * 128 + mf * 16 + rgrp * 4 + j;
        atomicAdd(&scores[m], s);
      }
    }
  }
#undef STAGE_A
#undef STAGE_B
}

// ---------------- merged softmax+attend+broadcast (bf16 feature reads) ------
__global__ __launch_bounds__(256) void attend_bcast(
    const float* __restrict__ sc_d, const us* __restrict__ dns_bf,
    const float* __restrict__ sc_i, const us* __restrict__ img_bf,
    float* __restrict__ out)
{
  __shared__ float p[256];
  __shared__ float red[256];
  const int b  = blockIdx.x;
  const int h0 = blockIdx.y * 512;
  const int z  = blockIdx.z;
  const int L  = z ? RR : SS;
  const float* scores = z ? sc_i : sc_d;
  const us*    feat   = z ? img_bf : dns_bf;
  float* outp = out + (z ? (size_t)0 : (size_t)BB * RR * Hdim);
  const int t = threadIdx.x;

  const float sc = (t < L) ? scores[b * L + t] : -1e30f;
  red[t] = sc;
  __syncthreads();
  for (int off = 128; off > 0; off >>= 1) {
    if (t < off) red[t] = fmaxf(red[t], red[t + off]);
    __syncthreads();
  }
  const float mx = red[0];
  __syncthreads();
  const float e = (t < L) ? __expf(sc - mx) : 0.f;
  red[t] = e;
  __syncthreads();
  for (int off = 128; off > 0; off >>= 1) {
    if (t < off) red[t] += red[t + off];
    __syncthreads();
  }
  p[t] = e / red[0];
  __syncthreads();

  const int h = h0 + 2 * t;
  const us* fb = feat + (size_t)b * L * Hdim + h;
  float a0 = 0.f, a1 = 0.f;
  #pragma unroll 8
  for (int s = 0; s < L; ++s) {
    const unsigned u = *(const unsigned*)(fb + (size_t)s * Hdim);
    const float f0 = __uint_as_float(u << 16);
    const float f1 = __uint_as_float(u & 0xffff0000u);
    a0 += p[s] * f0;
    a1 += p[s] * f1;
  }

  float* ob = outp + (size_t)b * RR * Hdim + h;
  const float2 v = make_float2(a0, a1);
  #pragma unroll 4
  for (int r = 0; r < RR; ++r)
    *(float2*)(ob + (size_t)r * Hdim) = v;
}

// ---------------- fallback path (ws too small): round-0 kernels -------------
__global__ __launch_bounds__(256) void gemm_score(
    const float* __restrict__ X, const float* __restrict__ W,
    const float* __restrict__ bias, const float* __restrict__ vatt,
    float* __restrict__ scores)
{
  __shared__ us Ash[128 * 32];
  __shared__ us Bsh[128 * 32];
  const int tid  = threadIdx.x;
  const int lane = tid & 63;
  const int wave = tid >> 6;
  const int waveM = (wave >> 1) * 64;
  const int waveN = (wave & 1) * 64;
  const long m0 = (long)blockIdx.x * 128;
  const long n0 = (long)blockIdx.y * 128;
  const int ldRow   = tid >> 3;
  const int ldChunk = (tid & 7) * 4;

  floatx4 acc[4][4];
  #pragma unroll
  for (int i = 0; i < 4; ++i)
    #pragma unroll
    for (int j = 0; j < 4; ++j)
      acc[i][j] = (floatx4){0.f, 0.f, 0.f, 0.f};

  const int frow = lane & 15;
  const int fk   = (lane >> 4) * 8;

  for (int k0 = 0; k0 < Hdim; k0 += 32) {
    __syncthreads();
    #pragma unroll
    for (int p = 0; p < 4; ++p) {
      const int r = ldRow + p * 32;
      const float4 av = *(const float4*)&X[(m0 + r) * Hdim + k0 + ldChunk];
      const float4 bv = *(const float4*)&W[(n0 + r) * Hdim + k0 + ldChunk];
      uint2 ap, bp;
      ap.x = (unsigned)f2bf(av.x) | ((unsigned)f2bf(av.y) << 16);
      ap.y = (unsigned)f2bf(av.z) | ((unsigned)f2bf(av.w) << 16);
      bp.x = (unsigned)f2bf(bv.x) | ((unsigned)f2bf(bv.y) << 16);
      bp.y = (unsigned)f2bf(bv.z) | ((unsigned)f2bf(bv.w) << 16);
      *(uint2*)&Ash[r * 32 + ldChunk] = ap;
      *(uint2*)&Bsh[r * 32 + ldChunk] = bp;
    }
    __syncthreads();
    short8 afr[4], bfr[4];
    #pragma unroll
    for (int mf = 0; mf < 4; ++mf)
      afr[mf] = *(const short8*)&Ash[(waveM + mf * 16 + frow) * 32 + fk];
    #pragma unroll
    for (int nf = 0; nf < 4; ++nf)
      bfr[nf] = *(const short8*)&Bsh[(waveN + nf * 16 + frow) * 32 + fk];
    #pragma unroll
    for (int mf = 0; mf < 4; ++mf)
      #pragma unroll
      for (int nf = 0; nf < 4; ++nf)
        acc[mf][nf] = __builtin_amdgcn_mfma_f32_16x16x32_bf16(afr[mf], bfr[nf], acc[mf][nf], 0, 0, 0);
  }

  const int rgrp = lane >> 4;
  #pragma unroll
  for (int mf = 0; mf < 4; ++mf) {
    float part[4] = {0.f, 0.f, 0.f, 0.f};
    #pragma unroll
    for (int nf = 0; nf < 4; ++nf) {
      const int n = (int)n0 + waveN + nf * 16 + (lane & 15);
      const float bi = bias[n];
      const float vv = vatt[n];
      #pragma unroll
      for (int j = 0; j < 4; ++j)
        part[j] += fast_tanh(acc[mf][nf][j] + bi) * vv;
    }
    #pragma unroll
    for (int j = 0; j < 4; ++j) {
      float s = part[j];
      s += __shfl_xor(s, 1);
      s += __shfl_xor(s, 2);
      s += __shfl_xor(s, 4);
      s += __shfl_xor(s, 8);
      if ((lane & 15) == 0) {
        const int m = (int)m0 + waveM + mf * 16 + rgrp * 4 + j;
        atomicAdd(&scores[m], s);
      }
    }
  }
}

template <int L>
__global__ __launch_bounds__(256) void softmax_attend(
    const float* __restrict__ scores, const float* __restrict__ feat,
    float* __restrict__ attended)
{
  __shared__ float p[256];
  __shared__ float red[256];
  const int b  = blockIdx.x;
  const int h0 = blockIdx.y * 256;
  const int t  = threadIdx.x;

  const float sc = (t < L) ? scores[b * L + t] : -1e30f;
  red[t] = sc;
  __syncthreads();
  for (int off = 128; off > 0; off >>= 1) {
    if (t < off) red[t] = fmaxf(red[t], red[t + off]);
    __syncthreads();
  }
  const float mx = red[0];
  __syncthreads();
  const float e = (t < L) ? __expf(sc - mx) : 0.f;
  red[t] = e;
  __syncthreads();
  for (int off = 128; off > 0; off >>= 1) {
    if (t < off) red[t] += red[t + off];
    __syncthreads();
  }
  p[t] = e / red[0];
  __syncthreads();

  const int h = h0 + t;
  const float* fb = feat + (size_t)b * L * Hdim + h;
  float acc = 0.f;
  #pragma unroll 4
  for (int s = 0; s < L; ++s)
    acc += p[s] * fb[(size_t)s * Hdim];
  attended[b * Hdim + h] = acc;
}

__global__ __launch_bounds__(256) void broadcast_out(
    const float4* __restrict__ att_img, const float4* __restrict__ att_dns,
    float4* __restrict__ out)
{
  const int H4 = Hdim / 4;
  const long region_sz = (long)BB * RR * H4;
  const long total = 2 * region_sz;
  for (long i = (long)blockIdx.x * blockDim.x + threadIdx.x; i < total;
       i += (long)gridDim.x * blockDim.x) {
    const int region = (i >= region_sz);
    const long rem = i - (long)region * region_sz;
    const int b  = (int)(rem / (RR * H4));
    const int h4 = (int)(rem % H4);
    const float4* src = region ? att_dns : att_img;
    out[i] = src[b * H4 + h4];
  }
}

extern "C" void kernel_launch(void* const* d_in, const int* in_sizes, int n_in,
                              void* d_out, int out_size, void* d_ws, size_t ws_size,
                              hipStream_t stream) {
  const float* dns    = (const float*)d_in[0];   // (B,S,H)
  const float* img    = (const float*)d_in[1];   // (B,R,H)
  const float* W_dns1 = (const float*)d_in[2];   // (H,H)
  const float* b_dns1 = (const float*)d_in[3];   // (H,)
  const float* w_att1 = (const float*)d_in[5];   // (2H,)
  const float* W_img2 = (const float*)d_in[8];   // (H,H)
  const float* b_img2 = (const float*)d_in[9];   // (H,)
  const float* w_att2 = (const float*)d_in[10];  // (2H,)

  const size_t dnsB = (size_t)MD * Hdim * 2;     // 33.55 MB
  const size_t imgB = (size_t)MI * Hdim * 2;     // 25.69 MB
  const size_t wB   = (size_t)Hdim * Hdim * 2;   //  2.10 MB
  const size_t scoresB = (16384 + 12544) * sizeof(float);
  const size_t need = dnsB + imgB + 2 * wB + scoresB;

  dim3 blk(256);

  if (ws_size >= need) {
    char* cur = (char*)d_ws;
    us* dns_bf = (us*)cur; cur += dnsB;
    us* img_bf = (us*)cur; cur += imgB;
    us* Wd1_bf = (us*)cur; cur += wB;
    us* Wi2_bf = (us*)cur; cur += wB;
    float* s_dns = (float*)cur;
    float* t_img = s_dns + 16384;

    prep_kernel<<<2048, blk, 0, stream>>>(
        (const float4*)dns, (const float4*)img,
        (const float4*)W_dns1, (const float4*)W_img2,
        (uint4*)dns_bf, (uint4*)img_bf, (uint4*)Wd1_bf, (uint4*)Wi2_bf,
        (float4*)s_dns);

    gemm_score_8p<<<dim3(NB1 + NB2), dim3(512), 0, stream>>>(
        dns_bf, Wd1_bf, b_dns1, w_att1 + Hdim, s_dns,
        img_bf, Wi2_bf, b_img2, w_att2 + Hdim, t_img);

    attend_bcast<<<dim3(BB, Hdim / 512, 2), blk, 0, stream>>>(
        s_dns, dns_bf, t_img, img_bf, (float*)d_out);
  } else {
    float* ws    = (float*)d_ws;
    float* s_dns = ws;
    float* t_img = ws + 16384;
    float* att_d = ws + 16384 + 12544;
    float* att_i = att_d + BB * Hdim;

    hipMemsetAsync(s_dns, 0, (16384 + 12544) * sizeof(float), stream);

    gemm_score<<<dim3(MD / 128, Hdim / 128), blk, 0, stream>>>(
        dns, W_dns1, b_dns1, w_att1 + Hdim, s_dns);
    gemm_score<<<dim3(MI / 128, Hdim / 128), blk, 0, stream>>>(
        img, W_img2, b_img2, w_att2 + Hdim, t_img);

    softmax_attend<SS><<<dim3(BB, Hdim / 256), blk, 0, stream>>>(s_dns, dns, att_d);
    softmax_attend<RR><<<dim3(BB, Hdim / 256), blk, 0, stream>>>(t_img, img, att_i);

    broadcast_out<<<2048, blk, 0, stream>>>((const float4*)att_i, (const float4*)att_d,
                                            (float4*)d_out);
  }
}

// Round 10
// 153.246 us; speedup vs baseline: 3.2480x; 3.2480x over previous
//
#include <hip/hip_runtime.h>

#define Hdim 1024
#define BB 64
#define SS 256
#define RR 196
#define MD (BB * SS)   // 16384
#define MI (BB * RR)   // 12544

typedef __attribute__((ext_vector_type(8))) short short8;
typedef __attribute__((ext_vector_type(4))) float floatx4;
typedef unsigned short us;

__device__ __forceinline__ unsigned short f2bf(float f) {
  unsigned int u = __float_as_uint(f);
  unsigned int r = 0x7FFFu + ((u >> 16) & 1u);
  return (unsigned short)((u + r) >> 16);
}

__device__ __forceinline__ float fast_tanh(float x) {
  x = fminf(15.f, fmaxf(-15.f, x));
  float e = __expf(2.f * x);
  return (e - 1.f) / (e + 1.f);
}

#define GLOAD16(g, l) __builtin_amdgcn_global_load_lds( \
    (const __attribute__((address_space(1))) unsigned int*)(g), \
    (__attribute__((address_space(3))) unsigned int*)(l), 16, 0, 0)

#define MEMFENCE asm volatile("" ::: "memory")
#define VMCNTA(n) asm volatile("s_waitcnt vmcnt(" #n ")" ::: "memory")

// ---------------- prep: all fp32->bf16 converts + zero scores, one kernel ---
__global__ __launch_bounds__(256) void prep_kernel(
    const float4* __restrict__ dns, const float4* __restrict__ img,
    const float4* __restrict__ Wd1, const float4* __restrict__ Wi2,
    uint4* __restrict__ dns_bf, uint4* __restrict__ img_bf,
    uint4* __restrict__ wd1_bf, uint4* __restrict__ wi2_bf,
    float4* __restrict__ scz)
{
  constexpr int N0 = (MD * Hdim) / 8;              // dns units (8 floats each)
  constexpr int N1 = N0 + (MI * Hdim) / 8;
  constexpr int N2 = N1 + (Hdim * Hdim) / 8;
  constexpr int N3 = N2 + (Hdim * Hdim) / 8;
  constexpr int N4 = N3 + (MD + MI) / 8;           // zero units
  const int stride = gridDim.x * 256;
  for (int i = blockIdx.x * 256 + threadIdx.x; i < N4; i += stride) {
    if (i < N3) {
      const float4* src; uint4* dst; int li;
      if (i < N0)      { src = dns; dst = dns_bf; li = i; }
      else if (i < N1) { src = img; dst = img_bf; li = i - N0; }
      else if (i < N2) { src = Wd1; dst = wd1_bf; li = i - N1; }
      else             { src = Wi2; dst = wi2_bf; li = i - N2; }
      const float4 a = src[2 * li];
      const float4 b = src[2 * li + 1];
      uint4 o;
      o.x = (unsigned)f2bf(a.x) | ((unsigned)f2bf(a.y) << 16);
      o.y = (unsigned)f2bf(a.z) | ((unsigned)f2bf(a.w) << 16);
      o.z = (unsigned)f2bf(b.x) | ((unsigned)f2bf(b.y) << 16);
      o.w = (unsigned)f2bf(b.z) | ((unsigned)f2bf(b.w) << 16);
      dst[li] = o;
    } else {
      const int li = i - N3;
      const float4 z4 = {0.f, 0.f, 0.f, 0.f};
      scz[2 * li]     = z4;
      scz[2 * li + 1] = z4;
    }
  }
}

// ---------------- 256x256 bf16 GEMM, BK=64, counted-vmcnt ring --------------
// 512 threads (8 waves 2Mx4N, wave tile 128x64), LDS 128KB:
//   A: [dbuf][band][wm][64r][64c]  (band0 = rows read in P1/P2, band1 = P3/P4)
//   B: [dbuf][256r][64c], read entirely into regs at P1 (8 x b128).
// Stage units: A-band = 2 loads/thread, B = 4 loads/thread.
// Ring (race-free because consumption is phase-ordered, barriers between the
// last reader phase and the overwriting issue):
//   T.P1: issue A1(T+1)   (band1 of dbuf d^1, freed at T-1.P4)
//   T.P2: issue B(T+2)    (B dbuf d, freed after T.P1 reg-reads)
//   T.P3: issue A0(T+2)   (band0 of dbuf d, freed after T.P2 reads)
// Waits (per-thread FIFO): W1 = vmcnt(8) @P4end guards next tile's B+A0;
// W2 = vmcnt(12) @P2end guards A1(T). Flight >= 5 phases; pipe NEVER drains
// below 8 loads mid-loop (tail peels to 8/2 then 0).
#define NB1 ((MD / 256) * 4)   // 256
#define NB2 ((MI / 256) * 4)   // 196

#define STAGE_A(d, b, kk) do { \
    GLOAD16(gAp[b][0] + (kk), &LDS[(d) * 16384 + (b) * 8192 + 0    + tid8]); \
    GLOAD16(gAp[b][1] + (kk), &LDS[(d) * 16384 + (b) * 8192 + 4096 + tid8]); } while (0)
#define STAGE_B(d, kk) do { \
    GLOAD16(gBp[0] + (kk), &LDS[32768 + (d) * 16384 + 0     + tid8]); \
    GLOAD16(gBp[1] + (kk), &LDS[32768 + (d) * 16384 + 4096  + tid8]); \
    GLOAD16(gBp[2] + (kk), &LDS[32768 + (d) * 16384 + 8192  + tid8]); \
    GLOAD16(gBp[3] + (kk), &LDS[32768 + (d) * 16384 + 12288 + tid8]); } while (0)

#define MFMA16(MB, KS) \
    _Pragma("unroll") for (int mf = 0; mf < 4; ++mf) \
    _Pragma("unroll") for (int nf = 0; nf < 4; ++nf) \
      acc[(MB) + mf][nf] = __builtin_amdgcn_mfma_f32_16x16x32_bf16(a[mf], bf[nf][KS], acc[(MB) + mf][nf], 0, 0, 0);

#define KTILE(d, kk1, kk2, DO_A1, DO_B2, DO_A0, W2N, W1N, DO_W1) do { \
    const int Ab = (d) * 16384 + wm * 4096 + frow * 64; \
    const int Bb = 32768 + (d) * 16384 + (wn * 64 + frow) * 64; \
    short8 a[4], bf[4][2]; \
    /* P1: stage A1(T+1); read A band0 ks0 + all B; MFMA mf0-3 ks0 */ \
    if (DO_A1) { STAGE_A((d) ^ 1, 1, kk1); } \
    _Pragma("unroll") for (int mf = 0; mf < 4; ++mf) \
      a[mf] = *(const short8*)&LDS[Ab + mf * 1024 + sl0]; \
    _Pragma("unroll") for (int nf = 0; nf < 4; ++nf) { \
      bf[nf][0] = *(const short8*)&LDS[Bb + nf * 1024 + sl0]; \
      bf[nf][1] = *(const short8*)&LDS[Bb + nf * 1024 + sl1]; } \
    MEMFENCE; __builtin_amdgcn_s_setprio(1); \
    MFMA16(0, 0); \
    __builtin_amdgcn_s_setprio(0); \
    MEMFENCE; __builtin_amdgcn_s_barrier(); MEMFENCE; \
    /* P2: stage B(T+2); read A band0 ks1; MFMA mf0-3 ks1; W2 */ \
    if (DO_B2) { STAGE_B(d, kk2); } \
    _Pragma("unroll") for (int mf = 0; mf < 4; ++mf) \
      a[mf] = *(const short8*)&LDS[Ab + mf * 1024 + sl1]; \
    MEMFENCE; __builtin_amdgcn_s_setprio(1); \
    MFMA16(0, 1); \
    __builtin_amdgcn_s_setprio(0); \
    VMCNTA(W2N); \
    MEMFENCE; __builtin_amdgcn_s_barrier(); MEMFENCE; \
    /* P3: stage A0(T+2); read A band1 ks0; MFMA mf4-7 ks0 */ \
    if (DO_A0) { STAGE_A(d, 0, kk2); } \
    _Pragma("unroll") for (int mf = 0; mf < 4; ++mf) \
      a[mf] = *(const short8*)&LDS[Ab + 8192 + mf * 1024 + sl0]; \
    MEMFENCE; __builtin_amdgcn_s_setprio(1); \
    MFMA16(4, 0); \
    __builtin_amdgcn_s_setprio(0); \
    MEMFENCE; __builtin_amdgcn_s_barrier(); MEMFENCE; \
    /* P4: read A band1 ks1; MFMA mf4-7 ks1; W1; boundary barrier */ \
    _Pragma("unroll") for (int mf = 0; mf < 4; ++mf) \
      a[mf] = *(const short8*)&LDS[Ab + 8192 + mf * 1024 + sl1]; \
    MEMFENCE; __builtin_amdgcn_s_setprio(1); \
    MFMA16(4, 1); \
    __builtin_amdgcn_s_setprio(0); \
    if (DO_W1) { VMCNTA(W1N); } \
    MEMFENCE; __builtin_amdgcn_s_barrier(); MEMFENCE; \
  } while (0)

__global__ __launch_bounds__(512, 2) void gemm_score_ring(
    const us* __restrict__ X1, const us* __restrict__ W1,
    const float* __restrict__ bias1, const float* __restrict__ v1, float* sc1,
    const us* __restrict__ X2, const us* __restrict__ W2,
    const float* __restrict__ bias2, const float* __restrict__ v2, float* sc2)
{
  __shared__ us LDS[65536];   // 128 KB

  // bijective XCD-chunked swizzle (m204): nwg=452, q=56, r=4
  const int nwg = gridDim.x;
  const int q = nwg >> 3, rr = nwg & 7;
  const int xcd = blockIdx.x & 7, idx = blockIdx.x >> 3;
  const int wg = (xcd < rr ? xcd * (q + 1) : rr * (q + 1) + (xcd - rr) * q) + idx;

  const us* Xb; const us* Wb; const float* bias; const float* vatt; float* scores;
  int mt, nt;
  if (wg < NB1) {
    Xb = X1; Wb = W1; bias = bias1; vatt = v1; scores = sc1;
    mt = wg >> 2; nt = wg & 3;
  } else {
    const int w2 = wg - NB1;
    Xb = X2; Wb = W2; bias = bias2; vatt = v2; scores = sc2;
    mt = w2 >> 2; nt = w2 & 3;
  }
  const long m0 = (long)mt * 256;
  const long n0 = (long)nt * 256;

  const int tid  = threadIdx.x;
  const int lane = tid & 63;
  const int w    = tid >> 6;     // wave 0..7
  const int wm   = w >> 2;       // 0..1
  const int wn   = w & 3;        // 0..3

  // staging geometry: 8 rows x 128B per load-instr per wave, XOR row&7 swizzle
  const int t8   = tid >> 3;
  const int scol = ((tid & 7) ^ (t8 & 7)) * 8;     // pre-swizzled source slot
  const int tid8 = tid * 8;                        // linear LDS dest (elems)
  // A physical banding: (b,l) -> logical rows {t8, 128+t8, 64+t8, 192+t8}
  const us* gAp[2][2] = {
    { Xb + (m0 + 0   + t8) * Hdim + scol, Xb + (m0 + 128 + t8) * Hdim + scol },
    { Xb + (m0 + 64  + t8) * Hdim + scol, Xb + (m0 + 192 + t8) * Hdim + scol } };
  const us* gBp[4] = {
    Wb + (n0 + 0   + t8) * Hdim + scol, Wb + (n0 + 64  + t8) * Hdim + scol,
    Wb + (n0 + 128 + t8) * Hdim + scol, Wb + (n0 + 192 + t8) * Hdim + scol };

  floatx4 acc[8][4];
  #pragma unroll
  for (int i = 0; i < 8; ++i)
    #pragma unroll
    for (int j = 0; j < 4; ++j)
      acc[i][j] = (floatx4){0.f, 0.f, 0.f, 0.f};

  const int frow = lane & 15;
  const int g    = lane >> 4;
  const int sw7  = frow & 7;
  const int sl0  = ((0 + g) ^ sw7) * 8;            // ks0 read slot (swizzled)
  const int sl1  = ((4 + g) ^ sw7) * 8;            // ks1 read slot

  // prologue: B(0), A0(0), A1(0), B(1), A0(1) -> 14 loads in flight
  STAGE_B(0, 0);
  STAGE_A(0, 0, 0);
  STAGE_A(0, 1, 0);
  STAGE_B(1, 64);
  STAGE_A(1, 0, 64);
  VMCNTA(8);                                       // B(0)+A0(0) landed
  MEMFENCE; __builtin_amdgcn_s_barrier(); MEMFENCE;

  #pragma unroll 1
  for (int T = 0; T < 14; ++T) {
    const int d = T & 1;
    KTILE(d, (T + 1) * 64, (T + 2) * 64, 1, 1, 1, 12, 8, 1);
  }
  // T = 14 (d=0): stage only A1(15); W2 allows {B15,A0_15,A1_15}=8; W1 allows {A1_15}=2
  KTILE(0, 15 * 64, 0, 1, 0, 0, 8, 2, 1);
  // T = 15 (d=1): no stages; W2 drains all (guards A1(15)); no W1
  KTILE(1, 0, 0, 0, 0, 0, 0, 0, 0);

  // fused epilogue: tanh(C + bias) . vatt -> per-row partial, atomicAdd.
  // C/D layout: col = lane&15, row = (lane>>4)*4 + j
  const int rgrp = lane >> 4;
  #pragma unroll
  for (int mf = 0; mf < 8; ++mf) {
    float part[4] = {0.f, 0.f, 0.f, 0.f};
    #pragma unroll
    for (int nf = 0; nf < 4; ++nf) {
      const int n = (int)n0 + wn * 64 + nf * 16 + (lane & 15);
      const float bi = bias[n];
      const float vv = vatt[n];
      #pragma unroll
      for (int j = 0; j < 4; ++j)
        part[j] += fast_tanh(acc[mf][nf][j] + bi) * vv;
    }
    #pragma unroll
    for (int j = 0; j < 4; ++j) {
      float s = part[j];
      s += __shfl_xor(s, 1);
      s += __shfl_xor(s, 2);
      s += __shfl_xor(s, 4);
      s += __shfl_xor(s, 8);
      if ((lane & 15) == 0) {
        const int m = (int)m0 + wm * 128 + mf * 16 + rgrp * 4 + j;
        atomicAdd(&scores[m], s);
      }
    }
  }
}

// ---------------- merged softmax+attend+broadcast (bf16 feature reads) ------
__global__ __launch_bounds__(256) void attend_bcast(
    const float* __restrict__ sc_d, const us* __restrict__ dns_bf,
    const float* __restrict__ sc_i, const us* __restrict__ img_bf,
    float* __restrict__ out)
{
  __shared__ float p[256];
  __shared__ float red[256];
  const int b  = blockIdx.x;
  const int h0 = blockIdx.y * 512;
  const int z  = blockIdx.z;
  const int L  = z ? RR : SS;
  const float* scores = z ? sc_i : sc_d;
  const us*    feat   = z ? img_bf : dns_bf;
  float* outp = out + (z ? (size_t)0 : (size_t)BB * RR * Hdim);
  const int t = threadIdx.x;

  const float sc = (t < L) ? scores[b * L + t] : -1e30f;
  red[t] = sc;
  __syncthreads();
  for (int off = 128; off > 0; off >>= 1) {
    if (t < off) red[t] = fmaxf(red[t], red[t + off]);
    __syncthreads();
  }
  const float mx = red[0];
  __syncthreads();
  const float e = (t < L) ? __expf(sc - mx) : 0.f;
  red[t] = e;
  __syncthreads();
  for (int off = 128; off > 0; off >>= 1) {
    if (t < off) red[t] += red[t + off];
    __syncthreads();
  }
  p[t] = e / red[0];
  __syncthreads();

  const int h = h0 + 2 * t;
  const us* fb = feat + (size_t)b * L * Hdim + h;
  float a0 = 0.f, a1 = 0.f;
  #pragma unroll 8
  for (int s = 0; s < L; ++s) {
    const unsigned u = *(const unsigned*)(fb + (size_t)s * Hdim);
    const float f0 = __uint_as_float(u << 16);
    const float f1 = __uint_as_float(u & 0xffff0000u);
    a0 += p[s] * f0;
    a1 += p[s] * f1;
  }

  float* ob = outp + (size_t)b * RR * Hdim + h;
  const float2 v = make_float2(a0, a1);
  #pragma unroll 4
  for (int r = 0; r < RR; ++r)
    *(float2*)(ob + (size_t)r * Hdim) = v;
}

// ---------------- fallback path (ws too small): round-0 kernels -------------
__global__ __launch_bounds__(256) void gemm_score(
    const float* __restrict__ X, const float* __restrict__ W,
    const float* __restrict__ bias, const float* __restrict__ vatt,
    float* __restrict__ scores)
{
  __shared__ us Ash[128 * 32];
  __shared__ us Bsh[128 * 32];
  const int tid  = threadIdx.x;
  const int lane = tid & 63;
  const int wave = tid >> 6;
  const int waveM = (wave >> 1) * 64;
  const int waveN = (wave & 1) * 64;
  const long m0 = (long)blockIdx.x * 128;
  const long n0 = (long)blockIdx.y * 128;
  const int ldRow   = tid >> 3;
  const int ldChunk = (tid & 7) * 4;

  floatx4 acc[4][4];
  #pragma unroll
  for (int i = 0; i < 4; ++i)
    #pragma unroll
    for (int j = 0; j < 4; ++j)
      acc[i][j] = (floatx4){0.f, 0.f, 0.f, 0.f};

  const int frow = lane & 15;
  const int fk   = (lane >> 4) * 8;

  for (int k0 = 0; k0 < Hdim; k0 += 32) {
    __syncthreads();
    #pragma unroll
    for (int p = 0; p < 4; ++p) {
      const int r = ldRow + p * 32;
      const float4 av = *(const float4*)&X[(m0 + r) * Hdim + k0 + ldChunk];
      const float4 bv = *(const float4*)&W[(n0 + r) * Hdim + k0 + ldChunk];
      uint2 ap, bp;
      ap.x = (unsigned)f2bf(av.x) | ((unsigned)f2bf(av.y) << 16);
      ap.y = (unsigned)f2bf(av.z) | ((unsigned)f2bf(av.w) << 16);
      bp.x = (unsigned)f2bf(bv.x) | ((unsigned)f2bf(bv.y) << 16);
      bp.y = (unsigned)f2bf(bv.z) | ((unsigned)f2bf(bv.w) << 16);
      *(uint2*)&Ash[r * 32 + ldChunk] = ap;
      *(uint2*)&Bsh[r * 32 + ldChunk] = bp;
    }
    __syncthreads();
    short8 afr[4], bfr[4];
    #pragma unroll
    for (int mf = 0; mf < 4; ++mf)
      afr[mf] = *(const short8*)&Ash[(waveM + mf * 16 + frow) * 32 + fk];
    #pragma unroll
    for (int nf = 0; nf < 4; ++nf)
      bfr[nf] = *(const short8*)&Bsh[(waveN + nf * 16 + frow) * 32 + fk];
    #pragma unroll
    for (int mf = 0; mf < 4; ++mf)
      #pragma unroll
      for (int nf = 0; nf < 4; ++nf)
        acc[mf][nf] = __builtin_amdgcn_mfma_f32_16x16x32_bf16(afr[mf], bfr[nf], acc[mf][nf], 0, 0, 0);
  }

  const int rgrp = lane >> 4;
  #pragma unroll
  for (int mf = 0; mf < 4; ++mf) {
    float part[4] = {0.f, 0.f, 0.f, 0.f};
    #pragma unroll
    for (int nf = 0; nf < 4; ++nf) {
      const int n = (int)n0 + waveN + nf * 16 + (lane & 15);
      const float bi = bias[n];
      const float vv = vatt[n];
      #pragma unroll
      for (int j = 0; j < 4; ++j)
        part[j] += fast_tanh(acc[mf][nf][j] + bi) * vv;
    }
    #pragma unroll
    for (int j = 0; j < 4; ++j) {
      float s = part[j];
      s += __shfl_xor(s, 1);
      s += __shfl_xor(s, 2);
      s += __shfl_xor(s, 4);
      s += __shfl_xor(s, 8);
      if ((lane & 15) == 0) {
        const int m = (int)m0 + waveM + mf * 16 + rgrp * 4 + j;
        atomicAdd(&scores[m], s);
      }
    }
  }
}

template <int L>
__global__ __launch_bounds__(256) void softmax_attend(
    const float* __restrict__ scores, const float* __restrict__ feat,
    float* __restrict__ attended)
{
  __shared__ float p[256];
  __shared__ float red[256];
  const int b  = blockIdx.x;
  const int h0 = blockIdx.y * 256;
  const int t  = threadIdx.x;

  const float sc = (t < L) ? scores[b * L + t] : -1e30f;
  red[t] = sc;
  __syncthreads();
  for (int off = 128; off > 0; off >>= 1) {
    if (t < off) red[t] = fmaxf(red[t], red[t + off]);
    __syncthreads();
  }
  const float mx = red[0];
  __syncthreads();
  const float e = (t < L) ? __expf(sc - mx) : 0.f;
  red[t] = e;
  __syncthreads();
  for (int off = 128; off > 0; off >>= 1) {
    if (t < off) red[t] += red[t + off];
    __syncthreads();
  }
  p[t] = e / red[0];
  __syncthreads();

  const int h = h0 + t;
  const float* fb = feat + (size_t)b * L * Hdim + h;
  float acc = 0.f;
  #pragma unroll 4
  for (int s = 0; s < L; ++s)
    acc += p[s] * fb[(size_t)s * Hdim];
  attended[b * Hdim + h] = acc;
}

__global__ __launch_bounds__(256) void broadcast_out(
    const float4* __restrict__ att_img, const float4* __restrict__ att_dns,
    float4* __restrict__ out)
{
  const int H4 = Hdim / 4;
  const long region_sz = (long)BB * RR * H4;
  const long total = 2 * region_sz;
  for (long i = (long)blockIdx.x * blockDim.x + threadIdx.x; i < total;
       i += (long)gridDim.x * blockDim.x) {
    const int region = (i >= region_sz);
    const long rem = i - (long)region * region_sz;
    const int b  = (int)(rem / (RR * H4));
    const int h4 = (int)(rem % H4);
    const float4* src = region ? att_dns : att_img;
    out[i] = src[b * H4 + h4];
  }
}

extern "C" void kernel_launch(void* const* d_in, const int* in_sizes, int n_in,
                              void* d_out, int out_size, void* d_ws, size_t ws_size,
                              hipStream_t stream) {
  const float* dns    = (const float*)d_in[0];   // (B,S,H)
  const float* img    = (const float*)d_in[1];   // (B,R,H)
  const float* W_dns1 = (const float*)d_in[2];   // (H,H)
  const float* b_dns1 = (const float*)d_in[3];   // (H,)
  const float* w_att1 = (const float*)d_in[5];   // (2H,)
  const float* W_img2 = (const float*)d_in[8];   // (H,H)
  const float* b_img2 = (const float*)d_in[9];   // (H,)
  const float* w_att2 = (const float*)d_in[10];  // (2H,)

  const size_t dnsB = (size_t)MD * Hdim * 2;     // 33.55 MB
  const size_t imgB = (size_t)MI * Hdim * 2;     // 25.69 MB
  const size_t wB   = (size_t)Hdim * Hdim * 2;   //  2.10 MB
  const size_t scoresB = (16384 + 12544) * sizeof(float);
  const size_t need = dnsB + imgB + 2 * wB + scoresB;

  dim3 blk(256);

  if (ws_size >= need) {
    char* cur = (char*)d_ws;
    us* dns_bf = (us*)cur; cur += dnsB;
    us* img_bf = (us*)cur; cur += imgB;
    us* Wd1_bf = (us*)cur; cur += wB;
    us* Wi2_bf = (us*)cur; cur += wB;
    float* s_dns = (float*)cur;
    float* t_img = s_dns + 16384;

    prep_kernel<<<2048, blk, 0, stream>>>(
        (const float4*)dns, (const float4*)img,
        (const float4*)W_dns1, (const float4*)W_img2,
        (uint4*)dns_bf, (uint4*)img_bf, (uint4*)Wd1_bf, (uint4*)Wi2_bf,
        (float4*)s_dns);

    gemm_score_ring<<<dim3(NB1 + NB2), dim3(512), 0, stream>>>(
        dns_bf, Wd1_bf, b_dns1, w_att1 + Hdim, s_dns,
        img_bf, Wi2_bf, b_img2, w_att2 + Hdim, t_img);

    attend_bcast<<<dim3(BB, Hdim / 512, 2), blk, 0, stream>>>(
        s_dns, dns_bf, t_img, img_bf, (float*)d_out);
  } else {
    float* ws    = (float*)d_ws;
    float* s_dns = ws;
    float* t_img = ws + 16384;
    float* att_d = ws + 16384 + 12544;
    float* att_i = att_d + BB * Hdim;

    hipMemsetAsync(s_dns, 0, (16384 + 12544) * sizeof(float), stream);

    gemm_score<<<dim3(MD / 128, Hdim / 128), blk, 0, stream>>>(
        dns, W_dns1, b_dns1, w_att1 + Hdim, s_dns);
    gemm_score<<<dim3(MI / 128, Hdim / 128), blk, 0, stream>>>(
        img, W_img2, b_img2, w_att2 + Hdim, t_img);

    softmax_attend<SS><<<dim3(BB, Hdim / 256), blk, 0, stream>>>(s_dns, dns, att_d);
    softmax_attend<RR><<<dim3(BB, Hdim / 256), blk, 0, stream>>>(t_img, img, att_i);

    broadcast_out<<<2048, blk, 0, stream>>>((const float4*)att_i, (const float4*)att_d,
                                            (float4*)d_out);
  }
}

// Round 11
// 153.210 us; speedup vs baseline: 3.2488x; 1.0002x over previous
//
#include <hip/hip_runtime.h>

#define Hdim 1024
#define BB 64
#define SS 256
#define RR 196
#define MD (BB * SS)   // 16384
#define MI (BB * RR)   // 12544

typedef __attribute__((ext_vector_type(8))) short short8;
typedef __attribute__((ext_vector_type(4))) float floatx4;
typedef unsigned short us;

__device__ __forceinline__ unsigned short f2bf(float f) {
  unsigned int u = __float_as_uint(f);
  unsigned int r = 0x7FFFu + ((u >> 16) & 1u);
  return (unsigned short)((u + r) >> 16);
}

__device__ __forceinline__ float fast_tanh(float x) {
  x = fminf(15.f, fmaxf(-15.f, x));
  float e = __expf(2.f * x);
  return (e - 1.f) / (e + 1.f);
}

#define GLOAD16(g, l) __builtin_amdgcn_global_load_lds( \
    (const __attribute__((address_space(1))) unsigned int*)(g), \
    (__attribute__((address_space(3))) unsigned int*)(l), 16, 0, 0)

#define MEMFENCE asm volatile("" ::: "memory")
#define VMCNTA(n) asm volatile("s_waitcnt vmcnt(" #n ")" ::: "memory")

// ---------------- prep: all fp32->bf16 converts + zero scores, one kernel ---
__global__ __launch_bounds__(256) void prep_kernel(
    const float4* __restrict__ dns, const float4* __restrict__ img,
    const float4* __restrict__ Wd1, const float4* __restrict__ Wi2,
    uint4* __restrict__ dns_bf, uint4* __restrict__ img_bf,
    uint4* __restrict__ wd1_bf, uint4* __restrict__ wi2_bf,
    float4* __restrict__ scz)
{
  constexpr int N0 = (MD * Hdim) / 8;              // dns units (8 floats each)
  constexpr int N1 = N0 + (MI * Hdim) / 8;
  constexpr int N2 = N1 + (Hdim * Hdim) / 8;
  constexpr int N3 = N2 + (Hdim * Hdim) / 8;
  constexpr int N4 = N3 + (MD + MI) / 8;           // zero units
  const int stride = gridDim.x * 256;
  for (int i = blockIdx.x * 256 + threadIdx.x; i < N4; i += stride) {
    if (i < N3) {
      const float4* src; uint4* dst; int li;
      if (i < N0)      { src = dns; dst = dns_bf; li = i; }
      else if (i < N1) { src = img; dst = img_bf; li = i - N0; }
      else if (i < N2) { src = Wd1; dst = wd1_bf; li = i - N1; }
      else             { src = Wi2; dst = wi2_bf; li = i - N2; }
      const float4 a = src[2 * li];
      const float4 b = src[2 * li + 1];
      uint4 o;
      o.x = (unsigned)f2bf(a.x) | ((unsigned)f2bf(a.y) << 16);
      o.y = (unsigned)f2bf(a.z) | ((unsigned)f2bf(a.w) << 16);
      o.z = (unsigned)f2bf(b.x) | ((unsigned)f2bf(b.y) << 16);
      o.w = (unsigned)f2bf(b.z) | ((unsigned)f2bf(b.w) << 16);
      dst[li] = o;
    } else {
      const int li = i - N3;
      const float4 z4 = {0.f, 0.f, 0.f, 0.f};
      scz[2 * li]     = z4;
      scz[2 * li + 1] = z4;
    }
  }
}

// ---------------- 256x256 bf16 GEMM, BK=64, counted-vmcnt ring --------------
// Tile-paired, one-round grid: 226 blocks (<=256 CUs, single dispatch round);
// each block runs TWO consecutive output tiles (2b, 2b+1) -- same mt,
// adjacent nt -> shared A panel (L2-hot second pass), fill/drain amortized.
// Inner ring identical to the verified round-10 schedule:
//   T.P1: issue A1(T+1); T.P2: issue B(T+2); T.P3: issue A0(T+2)
//   W2 = vmcnt(12) @P2end, W1 = vmcnt(8) @P4end (tail peels 8/2 then 0).
#define NB1 ((MD / 256) * 4)   // 256
#define NB2 ((MI / 256) * 4)   // 196
#define NBLK ((NB1 + NB2) / 2) // 226

#define STAGE_A(d, b, kk) do { \
    GLOAD16(gAp[b][0] + (kk), &LDS[(d) * 16384 + (b) * 8192 + 0    + tid8]); \
    GLOAD16(gAp[b][1] + (kk), &LDS[(d) * 16384 + (b) * 8192 + 4096 + tid8]); } while (0)
#define STAGE_B(d, kk) do { \
    GLOAD16(gBp[0] + (kk), &LDS[32768 + (d) * 16384 + 0     + tid8]); \
    GLOAD16(gBp[1] + (kk), &LDS[32768 + (d) * 16384 + 4096  + tid8]); \
    GLOAD16(gBp[2] + (kk), &LDS[32768 + (d) * 16384 + 8192  + tid8]); \
    GLOAD16(gBp[3] + (kk), &LDS[32768 + (d) * 16384 + 12288 + tid8]); } while (0)

#define MFMA16(MB, KS) \
    _Pragma("unroll") for (int mf = 0; mf < 4; ++mf) \
    _Pragma("unroll") for (int nf = 0; nf < 4; ++nf) \
      acc[(MB) + mf][nf] = __builtin_amdgcn_mfma_f32_16x16x32_bf16(a[mf], bfr[nf][KS], acc[(MB) + mf][nf], 0, 0, 0);

#define KTILE(d, kk1, kk2, DO_A1, DO_B2, DO_A0, W2N, W1N, DO_W1) do { \
    const int Ab = (d) * 16384 + wm * 4096 + frow * 64; \
    const int Bb = 32768 + (d) * 16384 + (wn * 64 + frow) * 64; \
    short8 a[4], bfr[4][2]; \
    /* P1: stage A1(T+1); read A band0 ks0 + all B; MFMA mf0-3 ks0 */ \
    if (DO_A1) { STAGE_A((d) ^ 1, 1, kk1); } \
    _Pragma("unroll") for (int mf = 0; mf < 4; ++mf) \
      a[mf] = *(const short8*)&LDS[Ab + mf * 1024 + sl0]; \
    _Pragma("unroll") for (int nf = 0; nf < 4; ++nf) { \
      bfr[nf][0] = *(const short8*)&LDS[Bb + nf * 1024 + sl0]; \
      bfr[nf][1] = *(const short8*)&LDS[Bb + nf * 1024 + sl1]; } \
    MEMFENCE; __builtin_amdgcn_s_setprio(1); \
    MFMA16(0, 0); \
    __builtin_amdgcn_s_setprio(0); \
    MEMFENCE; __builtin_amdgcn_s_barrier(); MEMFENCE; \
    /* P2: stage B(T+2); read A band0 ks1; MFMA mf0-3 ks1; W2 */ \
    if (DO_B2) { STAGE_B(d, kk2); } \
    _Pragma("unroll") for (int mf = 0; mf < 4; ++mf) \
      a[mf] = *(const short8*)&LDS[Ab + mf * 1024 + sl1]; \
    MEMFENCE; __builtin_amdgcn_s_setprio(1); \
    MFMA16(0, 1); \
    __builtin_amdgcn_s_setprio(0); \
    VMCNTA(W2N); \
    MEMFENCE; __builtin_amdgcn_s_barrier(); MEMFENCE; \
    /* P3: stage A0(T+2); read A band1 ks0; MFMA mf4-7 ks0 */ \
    if (DO_A0) { STAGE_A(d, 0, kk2); } \
    _Pragma("unroll") for (int mf = 0; mf < 4; ++mf) \
      a[mf] = *(const short8*)&LDS[Ab + 8192 + mf * 1024 + sl0]; \
    MEMFENCE; __builtin_amdgcn_s_setprio(1); \
    MFMA16(4, 0); \
    __builtin_amdgcn_s_setprio(0); \
    MEMFENCE; __builtin_amdgcn_s_barrier(); MEMFENCE; \
    /* P4: read A band1 ks1; MFMA mf4-7 ks1; W1; boundary barrier */ \
    _Pragma("unroll") for (int mf = 0; mf < 4; ++mf) \
      a[mf] = *(const short8*)&LDS[Ab + 8192 + mf * 1024 + sl1]; \
    MEMFENCE; __builtin_amdgcn_s_setprio(1); \
    MFMA16(4, 1); \
    __builtin_amdgcn_s_setprio(0); \
    if (DO_W1) { VMCNTA(W1N); } \
    MEMFENCE; __builtin_amdgcn_s_barrier(); MEMFENCE; \
  } while (0)

__global__ __launch_bounds__(512, 2) void gemm_score_ring(
    const us* __restrict__ X1, const us* __restrict__ W1,
    const float* __restrict__ bias1, const float* __restrict__ v1, float* sc1,
    const us* __restrict__ X2, const us* __restrict__ W2,
    const float* __restrict__ bias2, const float* __restrict__ v2, float* sc2)
{
  __shared__ us LDS[65536];   // 128 KB

  // bijective XCD-chunked swizzle (m204): nwg=226, q=28, r=2
  const int nwg = gridDim.x;
  const int q = nwg >> 3, rr = nwg & 7;
  const int xcd = blockIdx.x & 7, idx = blockIdx.x >> 3;
  const int wgb = (xcd < rr ? xcd * (q + 1) : rr * (q + 1) + (xcd - rr) * q) + idx;

  const int tid  = threadIdx.x;
  const int lane = tid & 63;
  const int w    = tid >> 6;     // wave 0..7
  const int wm   = w >> 2;       // 0..1
  const int wn   = w & 3;        // 0..3

  const int t8   = tid >> 3;
  const int scol = ((tid & 7) ^ (t8 & 7)) * 8;     // pre-swizzled source slot
  const int tid8 = tid * 8;                        // linear LDS dest (elems)

  const int frow = lane & 15;
  const int g    = lane >> 4;
  const int sw7  = frow & 7;
  const int sl0  = ((0 + g) ^ sw7) * 8;            // ks0 read slot (swizzled)
  const int sl1  = ((4 + g) ^ sw7) * 8;            // ks1 read slot
  const int rgrp = lane >> 4;

  #pragma unroll 1
  for (int half = 0; half < 2; ++half) {
    const int wg = wgb * 2 + half;

    const us* Xb; const us* Wb; const float* bias; const float* vatt; float* scores;
    int mt, nt;
    if (wg < NB1) {
      Xb = X1; Wb = W1; bias = bias1; vatt = v1; scores = sc1;
      mt = wg >> 2; nt = wg & 3;
    } else {
      const int w2 = wg - NB1;
      Xb = X2; Wb = W2; bias = bias2; vatt = v2; scores = sc2;
      mt = w2 >> 2; nt = w2 & 3;
    }
    const long m0 = (long)mt * 256;
    const long n0 = (long)nt * 256;

    // A physical banding: (b,l) -> logical rows {t8, 128+t8, 64+t8, 192+t8}
    const us* gAp[2][2] = {
      { Xb + (m0 + 0   + t8) * Hdim + scol, Xb + (m0 + 128 + t8) * Hdim + scol },
      { Xb + (m0 + 64  + t8) * Hdim + scol, Xb + (m0 + 192 + t8) * Hdim + scol } };
    const us* gBp[4] = {
      Wb + (n0 + 0   + t8) * Hdim + scol, Wb + (n0 + 64  + t8) * Hdim + scol,
      Wb + (n0 + 128 + t8) * Hdim + scol, Wb + (n0 + 192 + t8) * Hdim + scol };

    floatx4 acc[8][4];
    #pragma unroll
    for (int i = 0; i < 8; ++i)
      #pragma unroll
      for (int j = 0; j < 4; ++j)
        acc[i][j] = (floatx4){0.f, 0.f, 0.f, 0.f};

    // prologue: B(0), A0(0), A1(0), B(1), A0(1) -> 14 loads in flight
    // (residual epilogue atomics from the previous half only inflate vmcnt
    //  conservatively: they are OLDER FIFO entries, so waits remain safe.)
    STAGE_B(0, 0);
    STAGE_A(0, 0, 0);
    STAGE_A(0, 1, 0);
    STAGE_B(1, 64);
    STAGE_A(1, 0, 64);
    VMCNTA(8);                                       // B(0)+A0(0) landed
    MEMFENCE; __builtin_amdgcn_s_barrier(); MEMFENCE;

    #pragma unroll 1
    for (int T = 0; T < 14; ++T) {
      const int d = T & 1;
      KTILE(d, (T + 1) * 64, (T + 2) * 64, 1, 1, 1, 12, 8, 1);
    }
    // T = 14 (d=0): stage only A1(15)
    KTILE(0, 15 * 64, 0, 1, 0, 0, 8, 2, 1);
    // T = 15 (d=1): no stages; W2 drains all
    KTILE(1, 0, 0, 0, 0, 0, 0, 0, 0);

    // fused epilogue: tanh(C + bias) . vatt -> per-row partial, atomicAdd.
    // C/D layout: col = lane&15, row = (lane>>4)*4 + j
    #pragma unroll
    for (int mf = 0; mf < 8; ++mf) {
      float part[4] = {0.f, 0.f, 0.f, 0.f};
      #pragma unroll
      for (int nf = 0; nf < 4; ++nf) {
        const int n = (int)n0 + wn * 64 + nf * 16 + (lane & 15);
        const float bi = bias[n];
        const float vv = vatt[n];
        #pragma unroll
        for (int j = 0; j < 4; ++j)
          part[j] += fast_tanh(acc[mf][nf][j] + bi) * vv;
      }
      #pragma unroll
      for (int j = 0; j < 4; ++j) {
        float s = part[j];
        s += __shfl_xor(s, 1);
        s += __shfl_xor(s, 2);
        s += __shfl_xor(s, 4);
        s += __shfl_xor(s, 8);
        if ((lane & 15) == 0) {
          const int m = (int)m0 + wm * 128 + mf * 16 + rgrp * 4 + j;
          atomicAdd(&scores[m], s);
        }
      }
    }
    MEMFENCE; __builtin_amdgcn_s_barrier(); MEMFENCE;  // LDS safe for next half
  }
}

// ---------------- merged softmax+attend+broadcast (bf16 feature reads) ------
__global__ __launch_bounds__(256) void attend_bcast(
    const float* __restrict__ sc_d, const us* __restrict__ dns_bf,
    const float* __restrict__ sc_i, const us* __restrict__ img_bf,
    float* __restrict__ out)
{
  __shared__ float p[256];
  __shared__ float red[256];
  const int b  = blockIdx.x;
  const int h0 = blockIdx.y * 512;
  const int z  = blockIdx.z;
  const int L  = z ? RR : SS;
  const float* scores = z ? sc_i : sc_d;
  const us*    feat   = z ? img_bf : dns_bf;
  float* outp = out + (z ? (size_t)0 : (size_t)BB * RR * Hdim);
  const int t = threadIdx.x;

  const float sc = (t < L) ? scores[b * L + t] : -1e30f;
  red[t] = sc;
  __syncthreads();
  for (int off = 128; off > 0; off >>= 1) {
    if (t < off) red[t] = fmaxf(red[t], red[t + off]);
    __syncthreads();
  }
  const float mx = red[0];
  __syncthreads();
  const float e = (t < L) ? __expf(sc - mx) : 0.f;
  red[t] = e;
  __syncthreads();
  for (int off = 128; off > 0; off >>= 1) {
    if (t < off) red[t] += red[t + off];
    __syncthreads();
  }
  p[t] = e / red[0];
  __syncthreads();

  const int h = h0 + 2 * t;
  const us* fb = feat + (size_t)b * L * Hdim + h;
  float a0 = 0.f, a1 = 0.f;
  #pragma unroll 8
  for (int s = 0; s < L; ++s) {
    const unsigned u = *(const unsigned*)(fb + (size_t)s * Hdim);
    const float f0 = __uint_as_float(u << 16);
    const float f1 = __uint_as_float(u & 0xffff0000u);
    a0 += p[s] * f0;
    a1 += p[s] * f1;
  }

  float* ob = outp + (size_t)b * RR * Hdim + h;
  const float2 v = make_float2(a0, a1);
  #pragma unroll 4
  for (int r = 0; r < RR; ++r)
    *(float2*)(ob + (size_t)r * Hdim) = v;
}

// ---------------- fallback path (ws too small): round-0 kernels -------------
__global__ __launch_bounds__(256) void gemm_score(
    const float* __restrict__ X, const float* __restrict__ W,
    const float* __restrict__ bias, const float* __restrict__ vatt,
    float* __restrict__ scores)
{
  __shared__ us Ash[128 * 32];
  __shared__ us Bsh[128 * 32];
  const int tid  = threadIdx.x;
  const int lane = tid & 63;
  const int wave = tid >> 6;
  const int waveM = (wave >> 1) * 64;
  const int waveN = (wave & 1) * 64;
  const long m0 = (long)blockIdx.x * 128;
  const long n0 = (long)blockIdx.y * 128;
  const int ldRow   = tid >> 3;
  const int ldChunk = (tid & 7) * 4;

  floatx4 acc[4][4];
  #pragma unroll
  for (int i = 0; i < 4; ++i)
    #pragma unroll
    for (int j = 0; j < 4; ++j)
      acc[i][j] = (floatx4){0.f, 0.f, 0.f, 0.f};

  const int frow = lane & 15;
  const int fk   = (lane >> 4) * 8;

  for (int k0 = 0; k0 < Hdim; k0 += 32) {
    __syncthreads();
    #pragma unroll
    for (int p = 0; p < 4; ++p) {
      const int r = ldRow + p * 32;
      const float4 av = *(const float4*)&X[(m0 + r) * Hdim + k0 + ldChunk];
      const float4 bv = *(const float4*)&W[(n0 + r) * Hdim + k0 + ldChunk];
      uint2 ap, bp;
      ap.x = (unsigned)f2bf(av.x) | ((unsigned)f2bf(av.y) << 16);
      ap.y = (unsigned)f2bf(av.z) | ((unsigned)f2bf(av.w) << 16);
      bp.x = (unsigned)f2bf(bv.x) | ((unsigned)f2bf(bv.y) << 16);
      bp.y = (unsigned)f2bf(bv.z) | ((unsigned)f2bf(bv.w) << 16);
      *(uint2*)&Ash[r * 32 + ldChunk] = ap;
      *(uint2*)&Bsh[r * 32 + ldChunk] = bp;
    }
    __syncthreads();
    short8 afr[4], bfr[4];
    #pragma unroll
    for (int mf = 0; mf < 4; ++mf)
      afr[mf] = *(const short8*)&Ash[(waveM + mf * 16 + frow) * 32 + fk];
    #pragma unroll
    for (int nf = 0; nf < 4; ++nf)
      bfr[nf] = *(const short8*)&Bsh[(waveN + nf * 16 + frow) * 32 + fk];
    #pragma unroll
    for (int mf = 0; mf < 4; ++mf)
      #pragma unroll
      for (int nf = 0; nf < 4; ++nf)
        acc[mf][nf] = __builtin_amdgcn_mfma_f32_16x16x32_bf16(afr[mf], bfr[nf], acc[mf][nf], 0, 0, 0);
  }

  const int rgrp = lane >> 4;
  #pragma unroll
  for (int mf = 0; mf < 4; ++mf) {
    float part[4] = {0.f, 0.f, 0.f, 0.f};
    #pragma unroll
    for (int nf = 0; nf < 4; ++nf) {
      const int n = (int)n0 + waveN + nf * 16 + (lane & 15);
      const float bi = bias[n];
      const float vv = vatt[n];
      #pragma unroll
      for (int j = 0; j < 4; ++j)
        part[j] += fast_tanh(acc[mf][nf][j] + bi) * vv;
    }
    #pragma unroll
    for (int j = 0; j < 4; ++j) {
      float s = part[j];
      s += __shfl_xor(s, 1);
      s += __shfl_xor(s, 2);
      s += __shfl_xor(s, 4);
      s += __shfl_xor(s, 8);
      if ((lane & 15) == 0) {
        const int m = (int)m0 + waveM + mf * 16 + rgrp * 4 + j;
        atomicAdd(&scores[m], s);
      }
    }
  }
}

template <int L>
__global__ __launch_bounds__(256) void softmax_attend(
    const float* __restrict__ scores, const float* __restrict__ feat,
    float* __restrict__ attended)
{
  __shared__ float p[256];
  __shared__ float red[256];
  const int b  = blockIdx.x;
  const int h0 = blockIdx.y * 256;
  const int t  = threadIdx.x;

  const float sc = (t < L) ? scores[b * L + t] : -1e30f;
  red[t] = sc;
  __syncthreads();
  for (int off = 128; off > 0; off >>= 1) {
    if (t < off) red[t] = fmaxf(red[t], red[t + off]);
    __syncthreads();
  }
  const float mx = red[0];
  __syncthreads();
  const float e = (t < L) ? __expf(sc - mx) : 0.f;
  red[t] = e;
  __syncthreads();
  for (int off = 128; off > 0; off >>= 1) {
    if (t < off) red[t] += red[t + off];
    __syncthreads();
  }
  p[t] = e / red[0];
  __syncthreads();

  const int h = h0 + t;
  const float* fb = feat + (size_t)b * L * Hdim + h;
  float acc = 0.f;
  #pragma unroll 4
  for (int s = 0; s < L; ++s)
    acc += p[s] * fb[(size_t)s * Hdim];
  attended[b * Hdim + h] = acc;
}

__global__ __launch_bounds__(256) void broadcast_out(
    const float4* __restrict__ att_img, const float4* __restrict__ att_dns,
    float4* __restrict__ out)
{
  const int H4 = Hdim / 4;
  const long region_sz = (long)BB * RR * H4;
  const long total = 2 * region_sz;
  for (long i = (long)blockIdx.x * blockDim.x + threadIdx.x; i < total;
       i += (long)gridDim.x * blockDim.x) {
    const int region = (i >= region_sz);
    const long rem = i - (long)region * region_sz;
    const int b  = (int)(rem / (RR * H4));
    const int h4 = (int)(rem % H4);
    const float4* src = region ? att_dns : att_img;
    out[i] = src[b * H4 + h4];
  }
}

extern "C" void kernel_launch(void* const* d_in, const int* in_sizes, int n_in,
                              void* d_out, int out_size, void* d_ws, size_t ws_size,
                              hipStream_t stream) {
  const float* dns    = (const float*)d_in[0];   // (B,S,H)
  const float* img    = (const float*)d_in[1];   // (B,R,H)
  const float* W_dns1 = (const float*)d_in[2];   // (H,H)
  const float* b_dns1 = (const float*)d_in[3];   // (H,)
  const float* w_att1 = (const float*)d_in[5];   // (2H,)
  const float* W_img2 = (const float*)d_in[8];   // (H,H)
  const float* b_img2 = (const float*)d_in[9];   // (H,)
  const float* w_att2 = (const float*)d_in[10];  // (2H,)

  const size_t dnsB = (size_t)MD * Hdim * 2;     // 33.55 MB
  const size_t imgB = (size_t)MI * Hdim * 2;     // 25.69 MB
  const size_t wB   = (size_t)Hdim * Hdim * 2;   //  2.10 MB
  const size_t scoresB = (16384 + 12544) * sizeof(float);
  const size_t need = dnsB + imgB + 2 * wB + scoresB;

  dim3 blk(256);

  if (ws_size >= need) {
    char* cur = (char*)d_ws;
    us* dns_bf = (us*)cur; cur += dnsB;
    us* img_bf = (us*)cur; cur += imgB;
    us* Wd1_bf = (us*)cur; cur += wB;
    us* Wi2_bf = (us*)cur; cur += wB;
    float* s_dns = (float*)cur;
    float* t_img = s_dns + 16384;

    prep_kernel<<<2048, blk, 0, stream>>>(
        (const float4*)dns, (const float4*)img,
        (const float4*)W_dns1, (const float4*)W_img2,
        (uint4*)dns_bf, (uint4*)img_bf, (uint4*)Wd1_bf, (uint4*)Wi2_bf,
        (float4*)s_dns);

    gemm_score_ring<<<dim3(NBLK), dim3(512), 0, stream>>>(
        dns_bf, Wd1_bf, b_dns1, w_att1 + Hdim, s_dns,
        img_bf, Wi2_bf, b_img2, w_att2 + Hdim, t_img);

    attend_bcast<<<dim3(BB, Hdim / 512, 2), blk, 0, stream>>>(
        s_dns, dns_bf, t_img, img_bf, (float*)d_out);
  } else {
    float* ws    = (float*)d_ws;
    float* s_dns = ws;
    float* t_img = ws + 16384;
    float* att_d = ws + 16384 + 12544;
    float* att_i = att_d + BB * Hdim;

    hipMemsetAsync(s_dns, 0, (16384 + 12544) * sizeof(float), stream);

    gemm_score<<<dim3(MD / 128, Hdim / 128), blk, 0, stream>>>(
        dns, W_dns1, b_dns1, w_att1 + Hdim, s_dns);
    gemm_score<<<dim3(MI / 128, Hdim / 128), blk, 0, stream>>>(
        img, W_img2, b_img2, w_att2 + Hdim, t_img);

    softmax_attend<SS><<<dim3(BB, Hdim / 256), blk, 0, stream>>>(s_dns, dns, att_d);
    softmax_attend<RR><<<dim3(BB, Hdim / 256), blk, 0, stream>>>(t_img, img, att_i);

    broadcast_out<<<2048, blk, 0, stream>>>((const float4*)att_i, (const float4*)att_d,
                                            (float4*)d_out);
  }
}